// Round 11
// baseline (1310.828 us; speedup 1.0000x reference)
//
#include <hip/hip_runtime.h>
#include <hip/hip_bf16.h>

#define NTOK 4096
#define HID 2048
#define INTER 1408
#define NEXP 8
#define NPAIR 8192   // NTOK * TOP_K
#define NK1 64       // HID/32   (gemm1 BK=32)
#define NKT2 22      // INTER/64 (gemm2 BK=64)
#define G1SZ 24576   // gemm1 bytes/buffer: A 128x32 (8K) + B 256x32 (16K)
#define SZ2 16384    // gemm2 elems/buffer: A 128x64 + B 128x64

typedef short bf16x8 __attribute__((ext_vector_type(8)));
typedef float f32x4 __attribute__((ext_vector_type(4)));

__device__ __forceinline__ unsigned short f2bf(float f) {
  unsigned u = __builtin_bit_cast(unsigned, f);
  u += 0x7fffu + ((u >> 16) & 1u);   // round-to-nearest-even
  return (unsigned short)(u >> 16);
}
__device__ __forceinline__ float bf2f(unsigned short v) {
  return __builtin_bit_cast(float, (unsigned)v << 16);
}

__device__ __forceinline__ void gload16(const void* g, void* l) {
  __builtin_amdgcn_global_load_lds(
      (const __attribute__((address_space(1))) void*)g,
      (__attribute__((address_space(3))) void*)l, 16, 0, 0);
}

// m204 bijective XCD swizzle over the LIVE grid size nwg.
__device__ __forceinline__ int xcd_swz(int lin, int nwg) {
  int xcd = lin & 7, base = lin >> 3;
  int q = nwg >> 3, r = nwg & 7;
  return (xcd < r ? xcd * (q + 1) : r * (q + 1) + (xcd - r) * q) + base;
}

#define BAR __builtin_amdgcn_s_barrier()
#define SCHED0 __builtin_amdgcn_sched_barrier(0)
#define LGKM0 asm volatile("s_waitcnt lgkmcnt(0)" ::: "memory")
#define VM4 asm volatile("s_waitcnt vmcnt(4)" ::: "memory")
#define VM3 asm volatile("s_waitcnt vmcnt(3)" ::: "memory")
#define VM0 asm volatile("s_waitcnt vmcnt(0)" ::: "memory")
#define PRIO1 __builtin_amdgcn_s_setprio(1)
#define PRIO0 __builtin_amdgcn_s_setprio(0)

// ============ prep: block 0 routes; the rest convert hs + w1 ============
// ctrl ints: [0..7]=cnt [8..15]=off [16]=T (BM=128 tiles, T<=72)
//            [32..103]=tile_e  [104..175]=tile_mt
__global__ void k_prep(const float* __restrict__ hs, const float* __restrict__ w1,
                       unsigned short* __restrict__ dst,
                       const int* __restrict__ ids, const float* __restrict__ tw,
                       int* __restrict__ ctrl,
                       unsigned short* __restrict__ row_token,
                       float* __restrict__ row_weight) {
  if (blockIdx.x == 0) {
    __shared__ int cnt[NEXP], cur[NEXP];
    int t = threadIdx.x;
    if (t < NEXP) cnt[t] = 0;
    __syncthreads();
    for (int p = t; p < NPAIR; p += 512) atomicAdd(&cnt[ids[p]], 1);
    __syncthreads();
    if (t == 0) {
      int acc = 0, T = 0;
      for (int e = 0; e < NEXP; ++e) {
        cur[e] = acc;
        ctrl[e] = cnt[e];
        ctrl[8 + e] = acc;
        int n = (cnt[e] + 127) >> 7;
        for (int m = 0; m < n; ++m) { ctrl[32 + T] = e; ctrl[104 + T] = m; ++T; }
        acc += cnt[e];
      }
      ctrl[16] = T;
    }
    __syncthreads();
    for (int p = t; p < NPAIR; p += 512) {
      int e = ids[p];
      int pos = atomicAdd(&cur[e], 1);
      row_token[pos] = (unsigned short)(p >> 1);
      row_weight[pos] = tw[p];
    }
    return;
  }
  const int N0 = NTOK * HID / 4;
  const int N1 = N0 + NEXP * 2 * INTER * HID / 4;
  int stride = (gridDim.x - 1) * 512;
  for (int i = (blockIdx.x - 1) * 512 + threadIdx.x; i < N1; i += stride) {
    const float* s = (i < N0) ? hs : w1;
    int o = (i < N0) ? i : i - N0;
    float4 v = reinterpret_cast<const float4*>(s)[o];
    ushort4 u;
    u.x = f2bf(v.x); u.y = f2bf(v.y); u.z = f2bf(v.z); u.w = f2bf(v.w);
    reinterpret_cast<ushort4*>(dst)[i] = u;
  }
}

// ================= GEMM1: gate_up + SwiGLU =================
// BM=128 rows x BN=128 acts (256 gate_up chans), BK=32, 8 waves (2Mx4N),
// 48 KiB LDS double-buffer -> THREE blocks/CU (launch_bounds(512,6), 144 KiB
// LDS, VGPR<=85). Counted 2-deep pipeline: per iter {ds_read(cur); lgkm0;
// BAR; sched0; STAGE(cur, kt+2); 16 MFMA; vmcnt(3); BAR}.
// Blocks beyond the live tile grid convert w2 fp32->bf16 (gemm2-only input).

#define G1_STAGE(BB, kt) { \
  gload16(aptr + (size_t)(kt)*32, smem + (BB) + wvb16); \
  gload16(bptr0 + (size_t)(kt)*32, smem + (BB) + 8192 + wvb16); \
  gload16(bptr1 + (size_t)(kt)*32, smem + (BB) + 16384 + wvb16); }

#define G1_RD(BB) { \
  _Pragma("unroll") for (int m_ = 0; m_ < 4; ++m_) \
    af[m_] = *(const bf16x8*)(smem + (BB) + arow + m_*1024 + swz); \
  _Pragma("unroll") for (int n_ = 0; n_ < 2; ++n_) { \
    bg[n_] = *(const bf16x8*)(smem + (BB) + brow + n_*1024 + swz); \
    bu[n_] = *(const bf16x8*)(smem + (BB) + brow + 8192 + n_*1024 + swz); } }

#define G1_MMA \
  _Pragma("unroll") for (int m_ = 0; m_ < 4; ++m_) \
  _Pragma("unroll") for (int n_ = 0; n_ < 2; ++n_) { \
    accg[m_][n_] = __builtin_amdgcn_mfma_f32_16x16x32_bf16(af[m_], bg[n_], accg[m_][n_], 0, 0, 0); \
    accu[m_][n_] = __builtin_amdgcn_mfma_f32_16x16x32_bf16(af[m_], bu[n_], accu[m_][n_], 0, 0, 0); }

__global__ __launch_bounds__(512, 6) void k_gemm1(
    const unsigned short* __restrict__ hs,
    const unsigned short* __restrict__ w1,
    const float* __restrict__ w2f,
    unsigned short* __restrict__ w2b,
    const int* __restrict__ ctrl,
    const unsigned short* __restrict__ row_token,
    unsigned short* __restrict__ act) {
  const int T = ctrl[16];
  const int nwg = T * 11;
  const int lin = blockIdx.x;
  if (lin >= nwg) {
    // ---- w2 fp32 -> bf16 convert (tail blocks, fills idle CUs) ----
    const int NW2 = NEXP * HID * INTER / 4;
    int nc = gridDim.x - nwg;
    for (int i = (lin - nwg) * 512 + threadIdx.x; i < NW2; i += nc * 512) {
      float4 v = reinterpret_cast<const float4*>(w2f)[i];
      ushort4 u;
      u.x = f2bf(v.x); u.y = f2bf(v.y); u.z = f2bf(v.z); u.w = f2bf(v.w);
      reinterpret_cast<ushort4*>(w2b)[i] = u;
    }
    return;
  }
  const int wg = xcd_swz(lin, nwg);
  const int ti = wg / 11;
  const int nt = wg - ti * 11;
  const int e = ctrl[32 + ti], mt = ctrl[104 + ti];
  const int rows = ctrl[e], off_e = ctrl[8 + e];
  const int n0g = nt * 128;
  const unsigned short* w1e = w1 + (size_t)e * (2 * INTER * HID);

  __shared__ __align__(16) char smem[2 * G1SZ];  // 48 KiB -> 3 blocks/CU

  const int t = threadIdx.x;
  const int lane = t & 63, wv = t >> 6;
  const int wm = wv >> 2, wn = wv & 3;
  const int lm = lane & 15, hi4 = lane >> 4;
  const int wvb16 = (t & 448) * 16;
  const int arow = wm * 4096 + lm * 64;
  const int brow = 8192 + wn * 2048 + lm * 64;
  const int swz = (hi4 ^ ((lm >> 1) & 3)) * 16;

  // stage sources: global chunk pre-swizzled cl = (t&3)^((t>>3)&3) (rule #21)
  const unsigned short *aptr, *bptr0, *bptr1;
  {
    int cl8 = ((t & 3) ^ ((t >> 3) & 3)) * 8;
    int r = t >> 2;                       // 0..127
    int g0 = mt * 128 + r; if (g0 > rows - 1) g0 = rows - 1;
    aptr = hs + (size_t)row_token[off_e + g0] * HID + cl8;
    bptr0 = w1e + (size_t)(n0g + r) * HID + cl8;           // gate chans
    bptr1 = w1e + (size_t)(INTER + n0g + r) * HID + cl8;   // up chans
  }

  f32x4 accg[4][2], accu[4][2];
#pragma unroll
  for (int m = 0; m < 4; ++m)
#pragma unroll
    for (int n = 0; n < 2; ++n) {
      accg[m][n] = (f32x4){0.f, 0.f, 0.f, 0.f};
      accu[m][n] = (f32x4){0.f, 0.f, 0.f, 0.f};
    }
  bf16x8 af[4], bg[2], bu[2];

  // prologue: kt0 -> buf0, kt1 -> buf1 (3 loads each); kt0 landed at VM3
  G1_STAGE(0, 0)
  G1_STAGE(G1SZ, 1)
  VM3; BAR;

  unsigned cur = 0, oth = G1SZ;
  for (int kt = 0; kt < NK1; ++kt) {
    G1_RD(cur)
    LGKM0; BAR;    // all waves done reading cur
    SCHED0;
    if (kt + 2 < NK1) { G1_STAGE(cur, kt + 2) }   // refill cur (2-deep)
    PRIO1; G1_MMA PRIO0;
    if (kt < NK1 - 2) { VM3; BAR; }        // kt+1 landed; kt+2 in flight
    else if (kt == NK1 - 2) { VM0; BAR; }
    unsigned tmp = cur; cur = oth; oth = tmp;
  }

  // SwiGLU epilogue
#pragma unroll
  for (int m = 0; m < 4; ++m)
#pragma unroll
    for (int n = 0; n < 2; ++n) {
      int col = n0g + wn * 32 + n * 16 + lm;
#pragma unroll
      for (int j = 0; j < 4; ++j) {
        int grow = mt * 128 + wm * 64 + m * 16 + hi4 * 4 + j;
        if (grow < rows) {
          float g = accg[m][n][j];
          float u = accu[m][n][j];
          float a = g / (1.0f + __expf(-g)) * u;
          act[(size_t)(off_e + grow) * INTER + col] = f2bf(a);
        }
      }
    }
}

// ================= GEMM2: down proj + fused weighted scatter ==============
// BM=128, BN=128, BK=64, 8 waves, 64 KiB double-buffer, 2 blocks/CU.
// Epilogue: out[token] += weight * acc (fp32 atomicAdd; out pre-zeroed).
#define G2_RD_A(BB) { \
  _Pragma("unroll") for (int m_ = 0; m_ < 4; ++m_) { \
    af[m_][0] = *(const bf16x8*)(smem + (BB) + aoff + m_*1024 + csw0); \
    af[m_][1] = *(const bf16x8*)(smem + (BB) + aoff + m_*1024 + csw1); } }
#define G2_RD_B(BB) { \
  _Pragma("unroll") for (int n_ = 0; n_ < 2; ++n_) { \
    bfr[n_][0] = *(const bf16x8*)(smem + (BB) + boff + n_*1024 + csw0); \
    bfr[n_][1] = *(const bf16x8*)(smem + (BB) + boff + n_*1024 + csw1); } }

__global__ __launch_bounds__(512, 4) void k_gemm2(
    const unsigned short* __restrict__ act,
    const unsigned short* __restrict__ w2,
    const int* __restrict__ ctrl,
    const unsigned short* __restrict__ row_token,
    const float* __restrict__ row_weight,
    float* __restrict__ out) {
  const int T = ctrl[16];
  const int nwg = T * 16;
  const int lin = blockIdx.x;
  if (lin >= nwg) return;
  const int wg = xcd_swz(lin, nwg);
  const int ti = wg >> 4;
  const int nt = wg & 15;
  const int e = ctrl[32 + ti], mt = ctrl[104 + ti];
  const int rows = ctrl[e], off_e = ctrl[8 + e];
  const int n0 = nt * 128;
  const unsigned short* w2e = w2 + (size_t)e * (HID * INTER);

  __shared__ unsigned short smem[SZ2 * 2];  // 64 KiB

  const int t = threadIdx.x;
  const int lane = t & 63, wv = t >> 6;
  const int wm = wv >> 2, wn = wv & 3;
  const int lm = lane & 15, hi4 = lane >> 4;
  const int aoff = (wm * 64 + lm) * 64;
  const int boff = 8192 + (wn * 32 + lm) * 64;
  const int csw0 = (hi4 ^ (lm & 7)) * 8;
  const int csw1 = ((4 + hi4) ^ (lm & 7)) * 8;
  const int ldst = t * 8;

  const unsigned short* asrc[2];
#pragma unroll
  for (int i = 0; i < 2; ++i) {
    int p = i * 512 + t;
    int row = p >> 3, c = p & 7;
    int grow = mt * 128 + row;
    if (grow > rows - 1) grow = rows - 1;
    asrc[i] = act + (size_t)(off_e + grow) * INTER + (c ^ (row & 7)) * 8;
  }
  const unsigned short* bsrc[2];
#pragma unroll
  for (int i = 0; i < 2; ++i) {
    int p = i * 512 + t;
    int cb = p >> 3, c = p & 7;
    bsrc[i] = w2e + (size_t)(n0 + cb) * INTER + (c ^ (cb & 7)) * 8;
  }

#define G2_STAGE(BB, kt) { \
  gload16(asrc[0] + (size_t)(kt)*64, smem + (BB) + ldst); \
  gload16(asrc[1] + (size_t)(kt)*64, smem + (BB) + 4096 + ldst); \
  gload16(bsrc[0] + (size_t)(kt)*64, smem + (BB) + 8192 + ldst); \
  gload16(bsrc[1] + (size_t)(kt)*64, smem + (BB) + 12288 + ldst); }

  f32x4 acc[4][2];
#pragma unroll
  for (int m = 0; m < 4; ++m)
#pragma unroll
    for (int n = 0; n < 2; ++n) acc[m][n] = (f32x4){0.f, 0.f, 0.f, 0.f};
  bf16x8 af[4][2], bfr[2][2];

  G2_STAGE(0, 0)
  G2_STAGE(SZ2, 1)
  VM4; BAR;

  unsigned cur = 0, oth = SZ2;
  for (int kt = 0; kt < NKT2; ++kt) {
    G2_RD_A(cur)
    G2_RD_B(cur)
    LGKM0; BAR;
    SCHED0;
    if (kt + 2 < NKT2) { G2_STAGE(cur, kt + 2) }
    PRIO1;
#pragma unroll
    for (int kk = 0; kk < 2; ++kk)
#pragma unroll
      for (int m = 0; m < 4; ++m)
#pragma unroll
        for (int n = 0; n < 2; ++n)
          acc[m][n] = __builtin_amdgcn_mfma_f32_16x16x32_bf16(af[m][kk], bfr[n][kk], acc[m][n], 0, 0, 0);
    PRIO0;
    if (kt < NKT2 - 2) { VM4; BAR; }
    else if (kt == NKT2 - 2) { VM0; BAR; }
    unsigned tmp = cur; cur = oth; oth = tmp;
  }

  // fused weighted scatter: out[token, col] += w * acc
#pragma unroll
  for (int m = 0; m < 4; ++m)
#pragma unroll
    for (int n = 0; n < 2; ++n) {
      int col = n0 + wn * 32 + n * 16 + lm;
#pragma unroll
      for (int j = 0; j < 4; ++j) {
        int grow = mt * 128 + wm * 64 + m * 16 + hi4 * 4 + j;
        if (grow < rows) {
          int r = off_e + grow;
          float v = acc[m][n][j] * row_weight[r];
          atomicAdd(&out[(size_t)row_token[r] * HID + col], v);
        }
      }
    }
#undef G2_STAGE
}

extern "C" void kernel_launch(void* const* d_in, const int* in_sizes, int n_in,
                              void* d_out, int out_size, void* d_ws, size_t ws_size,
                              hipStream_t stream) {
  const float* hs_f = (const float*)d_in[0];
  const float* w1_f = (const float*)d_in[1];
  const float* w2_f = (const float*)d_in[2];
  const float* tw   = (const float*)d_in[3];
  const int*   tids = (const int*)d_in[4];
  float* out = (float*)d_out;

  // workspace layout (bytes) — same proven 178,323,712-byte footprint.
  // hs_b and w1_b are contiguous so prep converts both with one index space.
  char* ws = (char*)d_ws;
  unsigned short* hs_b = (unsigned short*)(ws);                   // 16,777,216
  unsigned short* w2_b = (unsigned short*)(ws + 109051904);       // 46,137,344
  unsigned short* act  = (unsigned short*)(ws + 155189248);       // 23,068,672
  int* ctrl = (int*)(ws + 178257920);                             // 1024 B
  unsigned short* row_token = (unsigned short*)(ws + 178258944);  // 16,384
  float* row_weight = (float*)(ws + 178275328);                   // 32,768

  hipMemsetAsync(d_out, 0, (size_t)NTOK * HID * sizeof(float), stream);

  // prep: block 0 = routing; blocks 1..2048 convert hs + w1 (contiguous dst)
  k_prep<<<2049, 512, 0, stream>>>(hs_f, w1_f, hs_b, tids, tw, ctrl,
                                   row_token, row_weight);

  // gemm1: worst-case live tiles T<=72 -> nwg<=792; remaining blocks cvt w2
  k_gemm1<<<1280, 512, 0, stream>>>(hs_b, (unsigned short*)(ws + 16777216), w2_f, w2_b,
                                    ctrl, row_token, act);
  k_gemm2<<<72 * 16, 512, 0, stream>>>(act, w2_b, ctrl, row_token, row_weight, out);
}

// Round 12
// 260.746 us; speedup vs baseline: 5.0272x; 5.0272x over previous
//
#include <hip/hip_runtime.h>
#include <hip/hip_bf16.h>

#define NTOK 4096
#define HID 2048
#define INTER 1408
#define NEXP 8
#define NPAIR 8192   // NTOK * TOP_K
#define NK1 64       // HID/32   (gemm1 BK=32)
#define NK2 44       // INTER/32 (gemm2 BK=32)
#define G1SZ 24576   // bytes/buffer: A 128x32 (8K) + B 256x32 (16K) — both GEMMs

typedef short bf16x8 __attribute__((ext_vector_type(8)));
typedef float f32x4 __attribute__((ext_vector_type(4)));

__device__ __forceinline__ unsigned short f2bf(float f) {
  unsigned u = __builtin_bit_cast(unsigned, f);
  u += 0x7fffu + ((u >> 16) & 1u);   // round-to-nearest-even
  return (unsigned short)(u >> 16);
}
__device__ __forceinline__ float bf2f(unsigned short v) {
  return __builtin_bit_cast(float, (unsigned)v << 16);
}

__device__ __forceinline__ void gload16(const void* g, void* l) {
  __builtin_amdgcn_global_load_lds(
      (const __attribute__((address_space(1))) void*)g,
      (__attribute__((address_space(3))) void*)l, 16, 0, 0);
}

// m204 bijective XCD swizzle over the LIVE grid size nwg.
__device__ __forceinline__ int xcd_swz(int lin, int nwg) {
  int xcd = lin & 7, base = lin >> 3;
  int q = nwg >> 3, r = nwg & 7;
  return (xcd < r ? xcd * (q + 1) : r * (q + 1) + (xcd - r) * q) + base;
}

#define BAR __builtin_amdgcn_s_barrier()
#define SCHED0 __builtin_amdgcn_sched_barrier(0)
#define LGKM0 asm volatile("s_waitcnt lgkmcnt(0)" ::: "memory")
#define VM3 asm volatile("s_waitcnt vmcnt(3)" ::: "memory")
#define VM0 asm volatile("s_waitcnt vmcnt(0)" ::: "memory")
#define PRIO1 __builtin_amdgcn_s_setprio(1)
#define PRIO0 __builtin_amdgcn_s_setprio(0)

// ============ prep: block 0 routes; the rest convert hs + w1 ============
// ctrl ints: [0..7]=cnt [8..15]=off [16]=T (BM=128 tiles, T<=72)
//            [32..103]=tile_e  [104..175]=tile_mt
__global__ void k_prep(const float* __restrict__ hs, const float* __restrict__ w1,
                       unsigned short* __restrict__ dst,
                       const int* __restrict__ ids, int* __restrict__ ctrl,
                       unsigned short* __restrict__ row_token,
                       unsigned short* __restrict__ inv_row) {
  if (blockIdx.x == 0) {
    __shared__ int cnt[NEXP], cur[NEXP];
    int t = threadIdx.x;
    if (t < NEXP) cnt[t] = 0;
    __syncthreads();
    for (int p = t; p < NPAIR; p += 512) atomicAdd(&cnt[ids[p]], 1);
    __syncthreads();
    if (t == 0) {
      int acc = 0, T = 0;
      for (int e = 0; e < NEXP; ++e) {
        cur[e] = acc;
        ctrl[e] = cnt[e];
        ctrl[8 + e] = acc;
        int n = (cnt[e] + 127) >> 7;
        for (int m = 0; m < n; ++m) { ctrl[32 + T] = e; ctrl[104 + T] = m; ++T; }
        acc += cnt[e];
      }
      ctrl[16] = T;
    }
    __syncthreads();
    for (int p = t; p < NPAIR; p += 512) {
      int e = ids[p];
      int pos = atomicAdd(&cur[e], 1);
      row_token[pos] = (unsigned short)(p >> 1);
      inv_row[p] = (unsigned short)pos;
    }
    return;
  }
  const int N0 = NTOK * HID / 4;
  const int N1 = N0 + NEXP * 2 * INTER * HID / 4;
  int stride = (gridDim.x - 1) * 512;
  for (int i = (blockIdx.x - 1) * 512 + threadIdx.x; i < N1; i += stride) {
    const float* s = (i < N0) ? hs : w1;
    int o = (i < N0) ? i : i - N0;
    float4 v = reinterpret_cast<const float4*>(s)[o];
    ushort4 u;
    u.x = f2bf(v.x); u.y = f2bf(v.y); u.z = f2bf(v.z); u.w = f2bf(v.w);
    reinterpret_cast<ushort4*>(dst)[i] = u;
  }
}

// ===== shared tile-loop machinery (proven r9-gemm1 geometry, 0 conflicts) ====
// LDS buffer (24 KiB): A rows 0..127 at r*64B; B chans 0..255 at 8192+br*64B.
// Read swizzle: (hi4 ^ ((lm>>1)&3))*16 ; stage source chunk: (t&3)^((t>>3)&3).
// Counted 2-deep pipeline: {8 ds_read(cur); lgkm0; BAR; sched0;
//  STAGE(cur, kt+2); 16 MFMA; vmcnt(3); BAR}.

#define T_STAGE(BB, kt) { \
  gload16(aptr + (size_t)(kt)*32, smem + (BB) + wvb16); \
  gload16(bptr0 + (size_t)(kt)*32, smem + (BB) + 8192 + wvb16); \
  gload16(bptr1 + (size_t)(kt)*32, smem + (BB) + 16384 + wvb16); }

#define T_RD(BB) { \
  _Pragma("unroll") for (int m_ = 0; m_ < 4; ++m_) \
    af[m_] = *(const bf16x8*)(smem + (BB) + arow + m_*1024 + swz); \
  _Pragma("unroll") for (int n_ = 0; n_ < 2; ++n_) { \
    b0[n_] = *(const bf16x8*)(smem + (BB) + brow + n_*1024 + swz); \
    b1[n_] = *(const bf16x8*)(smem + (BB) + brow + 8192 + n_*1024 + swz); } }

#define T_MMA \
  _Pragma("unroll") for (int m_ = 0; m_ < 4; ++m_) \
  _Pragma("unroll") for (int n_ = 0; n_ < 2; ++n_) { \
    acc0[m_][n_] = __builtin_amdgcn_mfma_f32_16x16x32_bf16(af[m_], b0[n_], acc0[m_][n_], 0, 0, 0); \
    acc1[m_][n_] = __builtin_amdgcn_mfma_f32_16x16x32_bf16(af[m_], b1[n_], acc1[m_][n_], 0, 0, 0); }

#define T_LOOP(NKT) \
  T_STAGE(0, 0) \
  T_STAGE(G1SZ, 1) \
  VM3; BAR; \
  unsigned cur = 0, oth = G1SZ; \
  for (int kt = 0; kt < (NKT); ++kt) { \
    T_RD(cur) \
    LGKM0; BAR; \
    SCHED0; \
    if (kt + 2 < (NKT)) { T_STAGE(cur, kt + 2) } \
    PRIO1; T_MMA PRIO0; \
    if (kt < (NKT) - 2) { VM3; BAR; } \
    else if (kt == (NKT) - 2) { VM0; BAR; } \
    unsigned tmp = cur; cur = oth; oth = tmp; \
  }

// ================= GEMM1: gate_up + SwiGLU =================
// BM=128 rows x 128 act-cols (B group0 = gate chans, group1 = up chans),
// BK=32, 8 waves (2Mx4N), 48 KiB dbuf, 2 blocks/CU ((512,4) — VGPR 64, r9).
// Blocks beyond the live tile grid convert w2 fp32->bf16 (gemm2-only input).
__global__ __launch_bounds__(512, 4) void k_gemm1(
    const unsigned short* __restrict__ hs,
    const unsigned short* __restrict__ w1,
    const float* __restrict__ w2f,
    unsigned short* __restrict__ w2b,
    const int* __restrict__ ctrl,
    const unsigned short* __restrict__ row_token,
    unsigned short* __restrict__ act) {
  const int T = ctrl[16];
  const int nwg = T * 11;
  const int lin = blockIdx.x;
  if (lin >= nwg) {
    // ---- w2 fp32 -> bf16 convert (tail blocks, fills idle CUs) ----
    const int NW2 = NEXP * HID * INTER / 4;
    int nc = gridDim.x - nwg;
    for (int i = (lin - nwg) * 512 + threadIdx.x; i < NW2; i += nc * 512) {
      float4 v = reinterpret_cast<const float4*>(w2f)[i];
      ushort4 u;
      u.x = f2bf(v.x); u.y = f2bf(v.y); u.z = f2bf(v.z); u.w = f2bf(v.w);
      reinterpret_cast<ushort4*>(w2b)[i] = u;
    }
    return;
  }
  const int wg = xcd_swz(lin, nwg);
  const int ti = wg / 11;
  const int nt = wg - ti * 11;
  const int e = ctrl[32 + ti], mt = ctrl[104 + ti];
  const int rows = ctrl[e], off_e = ctrl[8 + e];
  const int n0g = nt * 128;
  const unsigned short* w1e = w1 + (size_t)e * (2 * INTER * HID);

  __shared__ __align__(16) char smem[2 * G1SZ];  // 48 KiB

  const int t = threadIdx.x;
  const int lane = t & 63, wv = t >> 6;
  const int wm = wv >> 2, wn = wv & 3;
  const int lm = lane & 15, hi4 = lane >> 4;
  const int wvb16 = (t & 448) * 16;
  const int arow = wm * 4096 + lm * 64;
  const int brow = 8192 + wn * 2048 + lm * 64;
  const int swz = (hi4 ^ ((lm >> 1) & 3)) * 16;

  const unsigned short *aptr, *bptr0, *bptr1;
  {
    int cl8 = ((t & 3) ^ ((t >> 3) & 3)) * 8;
    int r = t >> 2;                       // 0..127
    int g0 = mt * 128 + r; if (g0 > rows - 1) g0 = rows - 1;
    aptr = hs + (size_t)row_token[off_e + g0] * HID + cl8;
    bptr0 = w1e + (size_t)(n0g + r) * HID + cl8;           // gate chans
    bptr1 = w1e + (size_t)(INTER + n0g + r) * HID + cl8;   // up chans
  }

  f32x4 acc0[4][2], acc1[4][2];
#pragma unroll
  for (int m = 0; m < 4; ++m)
#pragma unroll
    for (int n = 0; n < 2; ++n) {
      acc0[m][n] = (f32x4){0.f, 0.f, 0.f, 0.f};
      acc1[m][n] = (f32x4){0.f, 0.f, 0.f, 0.f};
    }
  bf16x8 af[4], b0[2], b1[2];

  T_LOOP(NK1)

  // SwiGLU epilogue: gate = acc0, up = acc1
#pragma unroll
  for (int m = 0; m < 4; ++m)
#pragma unroll
    for (int n = 0; n < 2; ++n) {
      int col = n0g + wn * 32 + n * 16 + lm;
#pragma unroll
      for (int j = 0; j < 4; ++j) {
        int grow = mt * 128 + wm * 64 + m * 16 + hi4 * 4 + j;
        if (grow < rows) {
          float g = acc0[m][n][j];
          float u = acc1[m][n][j];
          float a = g / (1.0f + __expf(-g)) * u;
          act[(size_t)(off_e + grow) * INTER + col] = f2bf(a);
        }
      }
    }
}

// ================= GEMM2: down proj =================
// Same transplanted geometry: BM=128 rows x 256 out-cols (group0 = cols
// n0..n0+127, group1 = n0+128..n0+255), BK=32, 48 KiB dbuf, (512,4).
// Blocks per tile: HID/256 = 8 -> T*8 blocks (~512 = 1 dispatch round).
__global__ __launch_bounds__(512, 4) void k_gemm2(
    const unsigned short* __restrict__ act,
    const unsigned short* __restrict__ w2,
    const int* __restrict__ ctrl,
    unsigned short* __restrict__ eo) {
  const int T = ctrl[16];
  const int nwg = T * 8;
  const int lin = blockIdx.x;
  if (lin >= nwg) return;
  const int wg = xcd_swz(lin, nwg);
  const int ti = wg >> 3;
  const int nt = wg & 7;
  const int e = ctrl[32 + ti], mt = ctrl[104 + ti];
  const int rows = ctrl[e], off_e = ctrl[8 + e];
  const int n0 = nt * 256;
  const unsigned short* w2e = w2 + (size_t)e * (HID * INTER);

  __shared__ __align__(16) char smem[2 * G1SZ];  // 48 KiB

  const int t = threadIdx.x;
  const int lane = t & 63, wv = t >> 6;
  const int wm = wv >> 2, wn = wv & 3;
  const int lm = lane & 15, hi4 = lane >> 4;
  const int wvb16 = (t & 448) * 16;
  const int arow = wm * 4096 + lm * 64;
  const int brow = 8192 + wn * 2048 + lm * 64;
  const int swz = (hi4 ^ ((lm >> 1) & 3)) * 16;

  const unsigned short *aptr, *bptr0, *bptr1;
  {
    int cl8 = ((t & 3) ^ ((t >> 3) & 3)) * 8;
    int r = t >> 2;                       // 0..127
    int g0 = mt * 128 + r; if (g0 > rows - 1) g0 = rows - 1;
    aptr = act + (size_t)(off_e + g0) * INTER + cl8;       // contiguous rows
    bptr0 = w2e + (size_t)(n0 + r) * INTER + cl8;          // cols n0+0..127
    bptr1 = w2e + (size_t)(n0 + 128 + r) * INTER + cl8;    // cols n0+128..255
  }

  f32x4 acc0[4][2], acc1[4][2];
#pragma unroll
  for (int m = 0; m < 4; ++m)
#pragma unroll
    for (int n = 0; n < 2; ++n) {
      acc0[m][n] = (f32x4){0.f, 0.f, 0.f, 0.f};
      acc1[m][n] = (f32x4){0.f, 0.f, 0.f, 0.f};
    }
  bf16x8 af[4], b0[2], b1[2];

  T_LOOP(NK2)

#pragma unroll
  for (int m = 0; m < 4; ++m)
#pragma unroll
    for (int n = 0; n < 2; ++n) {
      int col = n0 + wn * 32 + n * 16 + lm;
#pragma unroll
      for (int j = 0; j < 4; ++j) {
        int grow = mt * 128 + wm * 64 + m * 16 + hi4 * 4 + j;
        if (grow < rows) {
          size_t base = (size_t)(off_e + grow) * HID;
          eo[base + col] = f2bf(acc0[m][n][j]);
          eo[base + col + 128] = f2bf(acc1[m][n][j]);
        }
      }
    }
}

// ---------------- weighted combine: out = w0*eo[r0] + w1*eo[r1] ----------
__global__ void k_combine(const unsigned short* __restrict__ eo,
                          const float* __restrict__ tw,
                          const unsigned short* __restrict__ inv_row,
                          float* __restrict__ out) {
  int idx = blockIdx.x * blockDim.x + threadIdx.x;  // one bf16x8 chunk
  int tok = idx >> 8;        // HID/8 = 256 chunks per token
  int c8 = (idx & 255) * 8;
  int r0 = inv_row[tok * 2], r1 = inv_row[tok * 2 + 1];
  float w0 = tw[tok * 2], w1 = tw[tok * 2 + 1];
  bf16x8 v0 = *(const bf16x8*)(eo + (size_t)r0 * HID + c8);
  bf16x8 v1 = *(const bf16x8*)(eo + (size_t)r1 * HID + c8);
  float4 o0, o1;
  o0.x = w0 * bf2f((unsigned short)v0[0]) + w1 * bf2f((unsigned short)v1[0]);
  o0.y = w0 * bf2f((unsigned short)v0[1]) + w1 * bf2f((unsigned short)v1[1]);
  o0.z = w0 * bf2f((unsigned short)v0[2]) + w1 * bf2f((unsigned short)v1[2]);
  o0.w = w0 * bf2f((unsigned short)v0[3]) + w1 * bf2f((unsigned short)v1[3]);
  o1.x = w0 * bf2f((unsigned short)v0[4]) + w1 * bf2f((unsigned short)v1[4]);
  o1.y = w0 * bf2f((unsigned short)v0[5]) + w1 * bf2f((unsigned short)v1[5]);
  o1.z = w0 * bf2f((unsigned short)v0[6]) + w1 * bf2f((unsigned short)v1[6]);
  o1.w = w0 * bf2f((unsigned short)v0[7]) + w1 * bf2f((unsigned short)v1[7]);
  float4* op = reinterpret_cast<float4*>(out) + (size_t)tok * 512 + (idx & 255) * 2;
  op[0] = o0;
  op[1] = o1;
}

extern "C" void kernel_launch(void* const* d_in, const int* in_sizes, int n_in,
                              void* d_out, int out_size, void* d_ws, size_t ws_size,
                              hipStream_t stream) {
  const float* hs_f = (const float*)d_in[0];
  const float* w1_f = (const float*)d_in[1];
  const float* w2_f = (const float*)d_in[2];
  const float* tw   = (const float*)d_in[3];
  const int*   tids = (const int*)d_in[4];
  float* out = (float*)d_out;

  // workspace layout (bytes) — same proven 178,323,712-byte footprint.
  // hs_b and w1_b are contiguous so prep converts both with one index space.
  char* ws = (char*)d_ws;
  unsigned short* hs_b = (unsigned short*)(ws);                   // 16,777,216
  unsigned short* w2_b = (unsigned short*)(ws + 109051904);       // 46,137,344
  unsigned short* act  = (unsigned short*)(ws + 155189248);       // 23,068,672
  // eo overlays w1_b (dead after gemm1): 8192*2048*2 = 33,554,432 bytes
  unsigned short* eo   = (unsigned short*)(ws + 16777216);
  int* ctrl = (int*)(ws + 178257920);                             // 1024 B
  unsigned short* row_token = (unsigned short*)(ws + 178258944);  // 16,384
  unsigned short* inv_row   = (unsigned short*)(ws + 178275328);  // 16,384

  // prep: block 0 = routing; blocks 1..2048 convert hs + w1 (contiguous dst)
  k_prep<<<2049, 512, 0, stream>>>(hs_f, w1_f, hs_b, tids, ctrl, row_token, inv_row);

  // gemm1: worst-case live tiles T<=72 -> nwg<=792; remaining blocks cvt w2
  k_gemm1<<<1280, 512, 0, stream>>>(hs_b, (unsigned short*)(ws + 16777216), w2_f, w2_b,
                                    ctrl, row_token, act);
  // gemm2: 256-wide output tiles -> T*8 blocks (~512 = one dispatch round)
  k_gemm2<<<72 * 8, 512, 0, stream>>>(act, w2_b, ctrl, eo);
  k_combine<<<NTOK * HID / 8 / 256, 256, 0, stream>>>(eo, tw, inv_row, out);
}

// Round 13
// 257.789 us; speedup vs baseline: 5.0849x; 1.0115x over previous
//
#include <hip/hip_runtime.h>
#include <hip/hip_bf16.h>

#define NTOK 4096
#define HID 2048
#define INTER 1408
#define NEXP 8
#define NPAIR 8192   // NTOK * TOP_K
#define NKT1 32      // HID/64   (gemm1 8-phase, BK=64)
#define NK2 44       // INTER/32 (gemm2 BK=32)
#define G2SZ 24576   // gemm2 bytes/buffer: A 128x32 (8K) + B 256x32 (16K)

typedef short bf16x8 __attribute__((ext_vector_type(8)));
typedef float f32x4 __attribute__((ext_vector_type(4)));

__device__ __forceinline__ unsigned short f2bf(float f) {
  unsigned u = __builtin_bit_cast(unsigned, f);
  u += 0x7fffu + ((u >> 16) & 1u);   // round-to-nearest-even
  return (unsigned short)(u >> 16);
}
__device__ __forceinline__ float bf2f(unsigned short v) {
  return __builtin_bit_cast(float, (unsigned)v << 16);
}

__device__ __forceinline__ void gload16(const void* g, void* l) {
  __builtin_amdgcn_global_load_lds(
      (const __attribute__((address_space(1))) void*)g,
      (__attribute__((address_space(3))) void*)l, 16, 0, 0);
}

// m204 bijective XCD swizzle over the LIVE grid size nwg.
__device__ __forceinline__ int xcd_swz(int lin, int nwg) {
  int xcd = lin & 7, base = lin >> 3;
  int q = nwg >> 3, r = nwg & 7;
  return (xcd < r ? xcd * (q + 1) : r * (q + 1) + (xcd - r) * q) + base;
}

#define BAR __builtin_amdgcn_s_barrier()
#define SCHED0 __builtin_amdgcn_sched_barrier(0)
#define LGKM0 asm volatile("s_waitcnt lgkmcnt(0)" ::: "memory")
#define VM6 asm volatile("s_waitcnt vmcnt(6)" ::: "memory")
#define VM3 asm volatile("s_waitcnt vmcnt(3)" ::: "memory")
#define VM0 asm volatile("s_waitcnt vmcnt(0)" ::: "memory")
#define PRIO1 __builtin_amdgcn_s_setprio(1)
#define PRIO0 __builtin_amdgcn_s_setprio(0)

// ============ prep: block 0 routes (dual tile lists); rest convert hs+w1 ====
// ctrl ints: [0..7]=cnt [8..15]=off [16]=T1 (BM=256, <=40) [17]=T2 (BM=128, <=72)
//   t1_e at [32..71],  t1_mt at [72..111]
//   t2_e at [112..183], t2_mt at [184..255]
__global__ void k_prep(const float* __restrict__ hs, const float* __restrict__ w1,
                       unsigned short* __restrict__ dst,
                       const int* __restrict__ ids, int* __restrict__ ctrl,
                       unsigned short* __restrict__ row_token,
                       unsigned short* __restrict__ inv_row) {
  if (blockIdx.x == 0) {
    __shared__ int cnt[NEXP], cur[NEXP];
    int t = threadIdx.x;
    if (t < NEXP) cnt[t] = 0;
    __syncthreads();
    for (int p = t; p < NPAIR; p += 512) atomicAdd(&cnt[ids[p]], 1);
    __syncthreads();
    if (t == 0) {
      int acc = 0, T1 = 0, T2 = 0;
      for (int e = 0; e < NEXP; ++e) {
        cur[e] = acc;
        ctrl[e] = cnt[e];
        ctrl[8 + e] = acc;
        int n1 = (cnt[e] + 255) >> 8;
        for (int m = 0; m < n1; ++m) { ctrl[32 + T1] = e; ctrl[72 + T1] = m; ++T1; }
        int n2 = (cnt[e] + 127) >> 7;
        for (int m = 0; m < n2; ++m) { ctrl[112 + T2] = e; ctrl[184 + T2] = m; ++T2; }
        acc += cnt[e];
      }
      ctrl[16] = T1;
      ctrl[17] = T2;
    }
    __syncthreads();
    for (int p = t; p < NPAIR; p += 512) {
      int e = ids[p];
      int pos = atomicAdd(&cur[e], 1);
      row_token[pos] = (unsigned short)(p >> 1);
      inv_row[p] = (unsigned short)pos;
    }
    return;
  }
  const int N0 = NTOK * HID / 4;
  const int N1 = N0 + NEXP * 2 * INTER * HID / 4;
  int stride = (gridDim.x - 1) * 512;
  for (int i = (blockIdx.x - 1) * 512 + threadIdx.x; i < N1; i += stride) {
    const float* s = (i < N0) ? hs : w1;
    int o = (i < N0) ? i : i - N0;
    float4 v = reinterpret_cast<const float4*>(s)[o];
    ushort4 u;
    u.x = f2bf(v.x); u.y = f2bf(v.y); u.z = f2bf(v.z); u.w = f2bf(v.w);
    reinterpret_cast<ushort4*>(dst)[i] = u;
  }
}

// ================= GEMM1: gate_up + SwiGLU (8-phase, BM=256) =================
// r4-proven schedule: A gathered hs rows [256 x 64/step]; B = 256 gate_up
// chans. 8 waves (2M x 4N); LDS 128 KiB = 2 bufs x (A 256x64 + B 256x64).
// Per-phase interleave {ds_read || stage || MFMA}, counted VM6 at ph4/ph8.
// Blocks beyond the live tile grid convert w2 fp32->bf16 (gemm2-only input).

#define G1_STAGE_A(BB, u, ktile) \
  gload16(asrc[(u)*2+0] + (ktile)*64, lds + (BB) + ((u)*2+0)*4096 + wvb); \
  gload16(asrc[(u)*2+1] + (ktile)*64, lds + (BB) + ((u)*2+1)*4096 + wvb);
#define G1_STAGE_B(BB, u, ktile) \
  gload16(bsrc[(u)*2+0] + (ktile)*64, lds + (BB) + 16384 + ((u)*2+0)*4096 + wvb); \
  gload16(bsrc[(u)*2+1] + (ktile)*64, lds + (BB) + 16384 + ((u)*2+1)*4096 + wvb);

#define G1_READ_A(dst, BB, mh) \
  _Pragma("unroll") for (int m_ = 0; m_ < 4; ++m_) { \
    dst[m_][0] = *(const bf16x8*)(lds + (BB) + aoff + (mh)*8192 + m_*1024 + csw0); \
    dst[m_][1] = *(const bf16x8*)(lds + (BB) + aoff + (mh)*8192 + m_*1024 + csw1); \
  }
#define G1_READ_B(dst, BB, nh) \
  _Pragma("unroll") for (int n_ = 0; n_ < 2; ++n_) { \
    dst[n_][0] = *(const bf16x8*)(lds + (BB) + boff + (nh)*8192 + n_*1024 + csw0); \
    dst[n_][1] = *(const bf16x8*)(lds + (BB) + boff + (nh)*8192 + n_*1024 + csw1); \
  }

#define G1_MMA_Q(afr, bfr, mh, nh) \
  _Pragma("unroll") for (int m_ = 0; m_ < 4; ++m_) \
  _Pragma("unroll") for (int n_ = 0; n_ < 2; ++n_) { \
    acc[(mh)*4+m_][(nh)*2+n_] = __builtin_amdgcn_mfma_f32_16x16x32_bf16(afr[m_][0], bfr[n_][0], acc[(mh)*4+m_][(nh)*2+n_], 0, 0, 0); \
    acc[(mh)*4+m_][(nh)*2+n_] = __builtin_amdgcn_mfma_f32_16x16x32_bf16(afr[m_][1], bfr[n_][1], acc[(mh)*4+m_][(nh)*2+n_], 0, 0, 0); \
  }

// 8 phases / 2 K-tiles. Stage-after-last-read; counted VM6 at phases 4, 8.
#define G1_EIGHT(kt) \
  G1_READ_A(afM0, 0, 0) G1_READ_B(bfN0, 0, 0) G1_STAGE_B(32768, 1, (kt)+1); \
  BAR; LGKM0; PRIO1; G1_MMA_Q(afM0, bfN0, 0, 0) PRIO0; BAR; \
  G1_READ_B(bfN1, 0, 1) G1_STAGE_B(0, 0, (kt)+2); \
  BAR; LGKM0; PRIO1; G1_MMA_Q(afM0, bfN1, 0, 1) PRIO0; BAR; \
  G1_READ_A(afM1, 0, 1) G1_STAGE_A(0, 0, (kt)+2); \
  BAR; LGKM0; PRIO1; G1_MMA_Q(afM1, bfN1, 1, 1) PRIO0; BAR; \
  G1_STAGE_A(0, 1, (kt)+2); \
  BAR; LGKM0; PRIO1; G1_MMA_Q(afM1, bfN0, 1, 0) PRIO0; VM6; BAR; \
  G1_READ_A(afM0, 32768, 0) G1_READ_B(bfN0, 32768, 0) G1_STAGE_B(0, 1, (kt)+2); \
  BAR; LGKM0; PRIO1; G1_MMA_Q(afM0, bfN0, 0, 0) PRIO0; BAR; \
  G1_READ_B(bfN1, 32768, 1) G1_STAGE_B(32768, 0, (kt)+3); \
  BAR; LGKM0; PRIO1; G1_MMA_Q(afM0, bfN1, 0, 1) PRIO0; BAR; \
  G1_READ_A(afM1, 32768, 1) G1_STAGE_A(32768, 0, (kt)+3); \
  BAR; LGKM0; PRIO1; G1_MMA_Q(afM1, bfN1, 1, 1) PRIO0; BAR; \
  G1_STAGE_A(32768, 1, (kt)+3); \
  BAR; LGKM0; PRIO1; G1_MMA_Q(afM1, bfN0, 1, 0) PRIO0; VM6; BAR;

#define G1_EPI(kt) \
  G1_READ_A(afM0, 0, 0) G1_READ_B(bfN0, 0, 0) G1_STAGE_B(32768, 1, (kt)+1); \
  BAR; LGKM0; PRIO1; G1_MMA_Q(afM0, bfN0, 0, 0) PRIO0; BAR; \
  G1_READ_B(bfN1, 0, 1) \
  BAR; LGKM0; PRIO1; G1_MMA_Q(afM0, bfN1, 0, 1) PRIO0; BAR; \
  G1_READ_A(afM1, 0, 1) \
  BAR; LGKM0; PRIO1; G1_MMA_Q(afM1, bfN1, 1, 1) PRIO0; BAR; \
  BAR; LGKM0; PRIO1; G1_MMA_Q(afM1, bfN0, 1, 0) PRIO0; VM0; BAR; \
  G1_READ_A(afM0, 32768, 0) G1_READ_B(bfN0, 32768, 0) \
  BAR; LGKM0; PRIO1; G1_MMA_Q(afM0, bfN0, 0, 0) PRIO0; BAR; \
  G1_READ_B(bfN1, 32768, 1) \
  BAR; LGKM0; PRIO1; G1_MMA_Q(afM0, bfN1, 0, 1) PRIO0; BAR; \
  G1_READ_A(afM1, 32768, 1) \
  BAR; LGKM0; PRIO1; G1_MMA_Q(afM1, bfN1, 1, 1) PRIO0; BAR; \
  LGKM0; PRIO1; G1_MMA_Q(afM1, bfN0, 1, 0) PRIO0;

__global__ __launch_bounds__(512, 2) void k_gemm1(
    const unsigned short* __restrict__ hs,
    const unsigned short* __restrict__ w1,
    const float* __restrict__ w2f,
    unsigned short* __restrict__ w2b,
    const int* __restrict__ ctrl,
    const unsigned short* __restrict__ row_token,
    unsigned short* __restrict__ act) {
  const int T1 = ctrl[16];
  const int nwg = T1 * 11;
  const int lin = blockIdx.x;
  if (lin >= nwg) {
    // ---- w2 fp32 -> bf16 convert (tail blocks, fill round-2 idle CUs) ----
    const int NW2 = NEXP * HID * INTER / 4;
    int nc = gridDim.x - nwg;
    for (int i = (lin - nwg) * 512 + threadIdx.x; i < NW2; i += nc * 512) {
      float4 v = reinterpret_cast<const float4*>(w2f)[i];
      ushort4 u;
      u.x = f2bf(v.x); u.y = f2bf(v.y); u.z = f2bf(v.z); u.w = f2bf(v.w);
      reinterpret_cast<ushort4*>(w2b)[i] = u;
    }
    return;
  }
  const int wg = xcd_swz(lin, nwg);
  const int ti = wg / 11;
  const int nt = wg - ti * 11;
  const int e = ctrl[32 + ti], mt = ctrl[72 + ti];
  const int rows = ctrl[e], off_e = ctrl[8 + e];
  const int n0g = nt * 128;
  const unsigned short* w1e = w1 + (size_t)e * (2 * INTER * HID);

  __shared__ unsigned short smem[65536];  // 128 KiB
  unsigned short* lds = smem;

  const int t = threadIdx.x;
  const int lane = t & 63, wv = t >> 6;
  const int wm = wv >> 2, wn = wv & 3;
  const int lm = lane & 15, hi4 = lane >> 4;
  const int wvb = (t & 448) * 8;
  const int aoff = (wm * 64 + lm) * 64;
  const int boff = 16384 + (wn * 32 + lm) * 64;
  const int csw0 = (hi4 ^ (lm & 7)) * 8;
  const int csw1 = ((4 + hi4) ^ (lm & 7)) * 8;

  // A slot p -> row r(p) = ((p>>6)&1)*128 + (p>>7)*64 + (p&63); global source
  // carries the chunk-XOR swizzle (linear LDS dest, rule #21).
  const unsigned short* asrc[4];
#pragma unroll
  for (int i = 0; i < 4; ++i) {
    int p = i * 64 + (t >> 3);
    int r = ((p >> 6) & 1) * 128 + (p >> 7) * 64 + (p & 63);
    int grow = mt * 256 + r;
    if (grow > rows - 1) grow = rows - 1;
    int token = row_token[off_e + grow];
    asrc[i] = hs + (size_t)token * HID + ((t & 7) ^ (p & 7)) * 8;
  }
  // B slot p: nh=p>>7 (0=gate,1=up), wave wns=(p&127)>>5, idx=p&31.
  const unsigned short* bsrc[4];
#pragma unroll
  for (int i = 0; i < 4; ++i) {
    int p = i * 64 + (t >> 3);
    int nh = p >> 7, wns = (p & 127) >> 5, idx = p & 31;
    int c = n0g + wns * 32 + idx + nh * INTER;
    bsrc[i] = w1e + (size_t)c * HID + ((t & 7) ^ (p & 7)) * 8;
  }

  f32x4 acc[8][4];
#pragma unroll
  for (int i = 0; i < 8; ++i)
#pragma unroll
    for (int j = 0; j < 4; ++j) acc[i][j] = (f32x4){0.f, 0.f, 0.f, 0.f};
  bf16x8 afM0[4][2], afM1[4][2], bfN0[2][2], bfN1[2][2];

  // prologue: kt0 all 4 units + kt1 first 3; drain to 6 outstanding
  G1_STAGE_B(0, 0, 0) G1_STAGE_A(0, 0, 0) G1_STAGE_A(0, 1, 0) G1_STAGE_B(0, 1, 0)
  G1_STAGE_B(32768, 0, 1) G1_STAGE_A(32768, 0, 1) G1_STAGE_A(32768, 1, 1)
  VM6; BAR;

  for (int kt = 0; kt + 3 < NKT1; kt += 2) { G1_EIGHT(kt) }
  G1_EPI(NKT1 - 2)

  // SwiGLU epilogue: gate = acc[mf][n], up = acc[mf][2+n]
#pragma unroll
  for (int mh = 0; mh < 2; ++mh)
#pragma unroll
    for (int m = 0; m < 4; ++m)
#pragma unroll
      for (int n = 0; n < 2; ++n) {
        int col = n0g + wn * 32 + n * 16 + lm;
#pragma unroll
        for (int j = 0; j < 4; ++j) {
          int grow = mt * 256 + wm * 128 + mh * 64 + m * 16 + hi4 * 4 + j;
          if (grow < rows) {
            float g = acc[mh * 4 + m][n][j];
            float u = acc[mh * 4 + m][2 + n][j];
            float a = g / (1.0f + __expf(-g)) * u;
            act[(size_t)(off_e + grow) * INTER + col] = f2bf(a);
          }
        }
      }
}

// ================= GEMM2: down proj (r12-proven, BM=128 x 256 cols) ========
// BK=32, 8 waves, 48 KiB dbuf, (512,4); counted 2-deep VM3 pipeline.
#define T_STAGE(BB, kt) { \
  gload16(aptr + (size_t)(kt)*32, smem + (BB) + wvb16); \
  gload16(bptr0 + (size_t)(kt)*32, smem + (BB) + 8192 + wvb16); \
  gload16(bptr1 + (size_t)(kt)*32, smem + (BB) + 16384 + wvb16); }

#define T_RD(BB) { \
  _Pragma("unroll") for (int m_ = 0; m_ < 4; ++m_) \
    af[m_] = *(const bf16x8*)(smem + (BB) + arow + m_*1024 + swz); \
  _Pragma("unroll") for (int n_ = 0; n_ < 2; ++n_) { \
    b0[n_] = *(const bf16x8*)(smem + (BB) + brow + n_*1024 + swz); \
    b1[n_] = *(const bf16x8*)(smem + (BB) + brow + 8192 + n_*1024 + swz); } }

#define T_MMA \
  _Pragma("unroll") for (int m_ = 0; m_ < 4; ++m_) \
  _Pragma("unroll") for (int n_ = 0; n_ < 2; ++n_) { \
    acc0[m_][n_] = __builtin_amdgcn_mfma_f32_16x16x32_bf16(af[m_], b0[n_], acc0[m_][n_], 0, 0, 0); \
    acc1[m_][n_] = __builtin_amdgcn_mfma_f32_16x16x32_bf16(af[m_], b1[n_], acc1[m_][n_], 0, 0, 0); }

__global__ __launch_bounds__(512, 4) void k_gemm2(
    const unsigned short* __restrict__ act,
    const unsigned short* __restrict__ w2,
    const int* __restrict__ ctrl,
    unsigned short* __restrict__ eo) {
  const int T2 = ctrl[17];
  const int nwg = T2 * 8;
  const int lin = blockIdx.x;
  if (lin >= nwg) return;
  const int wg = xcd_swz(lin, nwg);
  const int ti = wg >> 3;
  const int nt = wg & 7;
  const int e = ctrl[112 + ti], mt = ctrl[184 + ti];
  const int rows = ctrl[e], off_e = ctrl[8 + e];
  const int n0 = nt * 256;
  const unsigned short* w2e = w2 + (size_t)e * (HID * INTER);

  __shared__ __align__(16) char smem[2 * G2SZ];  // 48 KiB

  const int t = threadIdx.x;
  const int lane = t & 63, wv = t >> 6;
  const int wm = wv >> 2, wn = wv & 3;
  const int lm = lane & 15, hi4 = lane >> 4;
  const int wvb16 = (t & 448) * 16;
  const int arow = wm * 4096 + lm * 64;
  const int brow = 8192 + wn * 2048 + lm * 64;
  const int swz = (hi4 ^ ((lm >> 1) & 3)) * 16;

  const unsigned short *aptr, *bptr0, *bptr1;
  {
    int cl8 = ((t & 3) ^ ((t >> 3) & 3)) * 8;
    int r = t >> 2;                       // 0..127
    int g0 = mt * 128 + r; if (g0 > rows - 1) g0 = rows - 1;
    aptr = act + (size_t)(off_e + g0) * INTER + cl8;       // contiguous rows
    bptr0 = w2e + (size_t)(n0 + r) * INTER + cl8;          // cols n0+0..127
    bptr1 = w2e + (size_t)(n0 + 128 + r) * INTER + cl8;    // cols n0+128..255
  }

  f32x4 acc0[4][2], acc1[4][2];
#pragma unroll
  for (int m = 0; m < 4; ++m)
#pragma unroll
    for (int n = 0; n < 2; ++n) {
      acc0[m][n] = (f32x4){0.f, 0.f, 0.f, 0.f};
      acc1[m][n] = (f32x4){0.f, 0.f, 0.f, 0.f};
    }
  bf16x8 af[4], b0[2], b1[2];

  T_STAGE(0, 0)
  T_STAGE(G2SZ, 1)
  VM3; BAR;
  unsigned cur = 0, oth = G2SZ;
  for (int kt = 0; kt < NK2; ++kt) {
    T_RD(cur)
    LGKM0; BAR;
    SCHED0;
    if (kt + 2 < NK2) { T_STAGE(cur, kt + 2) }
    PRIO1; T_MMA PRIO0;
    if (kt < NK2 - 2) { VM3; BAR; }
    else if (kt == NK2 - 2) { VM0; BAR; }
    unsigned tmp = cur; cur = oth; oth = tmp;
  }

#pragma unroll
  for (int m = 0; m < 4; ++m)
#pragma unroll
    for (int n = 0; n < 2; ++n) {
      int col = n0 + wn * 32 + n * 16 + lm;
#pragma unroll
      for (int j = 0; j < 4; ++j) {
        int grow = mt * 128 + wm * 64 + m * 16 + hi4 * 4 + j;
        if (grow < rows) {
          size_t base = (size_t)(off_e + grow) * HID;
          eo[base + col] = f2bf(acc0[m][n][j]);
          eo[base + col + 128] = f2bf(acc1[m][n][j]);
        }
      }
    }
}

// ---------------- weighted combine: out = w0*eo[r0] + w1*eo[r1] ----------
__global__ void k_combine(const unsigned short* __restrict__ eo,
                          const float* __restrict__ tw,
                          const unsigned short* __restrict__ inv_row,
                          float* __restrict__ out) {
  int idx = blockIdx.x * blockDim.x + threadIdx.x;  // one bf16x8 chunk
  int tok = idx >> 8;        // HID/8 = 256 chunks per token
  int c8 = (idx & 255) * 8;
  int r0 = inv_row[tok * 2], r1 = inv_row[tok * 2 + 1];
  float w0 = tw[tok * 2], w1 = tw[tok * 2 + 1];
  bf16x8 v0 = *(const bf16x8*)(eo + (size_t)r0 * HID + c8);
  bf16x8 v1 = *(const bf16x8*)(eo + (size_t)r1 * HID + c8);
  float4 o0, o1;
  o0.x = w0 * bf2f((unsigned short)v0[0]) + w1 * bf2f((unsigned short)v1[0]);
  o0.y = w0 * bf2f((unsigned short)v0[1]) + w1 * bf2f((unsigned short)v1[1]);
  o0.z = w0 * bf2f((unsigned short)v0[2]) + w1 * bf2f((unsigned short)v1[2]);
  o0.w = w0 * bf2f((unsigned short)v0[3]) + w1 * bf2f((unsigned short)v1[3]);
  o1.x = w0 * bf2f((unsigned short)v0[4]) + w1 * bf2f((unsigned short)v1[4]);
  o1.y = w0 * bf2f((unsigned short)v0[5]) + w1 * bf2f((unsigned short)v1[5]);
  o1.z = w0 * bf2f((unsigned short)v0[6]) + w1 * bf2f((unsigned short)v1[6]);
  o1.w = w0 * bf2f((unsigned short)v0[7]) + w1 * bf2f((unsigned short)v1[7]);
  float4* op = reinterpret_cast<float4*>(out) + (size_t)tok * 512 + (idx & 255) * 2;
  op[0] = o0;
  op[1] = o1;
}

extern "C" void kernel_launch(void* const* d_in, const int* in_sizes, int n_in,
                              void* d_out, int out_size, void* d_ws, size_t ws_size,
                              hipStream_t stream) {
  const float* hs_f = (const float*)d_in[0];
  const float* w1_f = (const float*)d_in[1];
  const float* w2_f = (const float*)d_in[2];
  const float* tw   = (const float*)d_in[3];
  const int*   tids = (const int*)d_in[4];
  float* out = (float*)d_out;

  // workspace layout (bytes) — same proven 178,323,712-byte footprint.
  // hs_b and w1_b are contiguous so prep converts both with one index space.
  char* ws = (char*)d_ws;
  unsigned short* hs_b = (unsigned short*)(ws);                   // 16,777,216
  unsigned short* w1_b = (unsigned short*)(ws + 16777216);        // 92,274,688
  unsigned short* w2_b = (unsigned short*)(ws + 109051904);       // 46,137,344
  unsigned short* act  = (unsigned short*)(ws + 155189248);       // 23,068,672
  // eo overlays w1_b (dead after gemm1): 8192*2048*2 = 33,554,432 bytes
  unsigned short* eo   = (unsigned short*)(ws + 16777216);
  int* ctrl = (int*)(ws + 178257920);                             // 1024 B
  unsigned short* row_token = (unsigned short*)(ws + 178258944);  // 16,384
  unsigned short* inv_row   = (unsigned short*)(ws + 178275328);  // 16,384

  // prep: block 0 = routing; blocks 1..2048 convert hs + w1 (contiguous dst)
  k_prep<<<2049, 512, 0, stream>>>(hs_f, w1_f, hs_b, tids, ctrl, row_token, inv_row);

  // gemm1: 8-phase BM=256 tiles (nwg = T1*11 <= 440); tail blocks convert w2
  k_gemm1<<<1024, 512, 0, stream>>>(hs_b, w1_b, w2_f, w2_b, ctrl, row_token, act);
  // gemm2: 256-wide output tiles -> T2*8 blocks (~512 = one dispatch round)
  k_gemm2<<<72 * 8, 512, 0, stream>>>(act, w2_b, ctrl, eo);
  k_combine<<<NTOK * HID / 8 / 256, 256, 0, stream>>>(eo, tw, inv_row, out);
}